// Round 4
// baseline (425.944 us; speedup 1.0000x reference)
//
#include <hip/hip_runtime.h>

// Conv1d as implicit GEMM on MFMA bf16 — R4.
// out[n,f,t] = sum_{c,k} x[n,c,t+k] * w[f,c,k] + b[f]
// N=32, C=64, W=4096, F=128, WW=64, out_W=4033. Output fp32.
//
// R4: wave tile 128t x 64f, t-stride-8 A mapping (t = 8*col + ms, ms 0..7):
//     per K=32 step a wave needs ONE 16-short aligned window -> 2 ds_read_b128
//     serve 32 MFMAs (even-ms frags are register aliases, odd-ms funnel shifts).
//     B-frags reused across 8 ms. LDS-transpose epilogue -> coalesced float4
//     stores (fixes R3's 2.6x HBM write amplification from strided scatter).

#define C_TOT   64
#define F_TOT   128
#define KW      64
#define OUT_W   4033
#define W_IN    4096
#define N_BATCH 32
#define T_BLK   256
#define XROW    4352          // padded bf16 x row length (shorts)
#define CH      2             // channels per pipeline stage
#define TRS     260           // transpose LDS row stride (dwords): 256 + 4 pad

typedef __attribute__((ext_vector_type(8))) short  short8;
typedef __attribute__((ext_vector_type(4))) float  floatx4;

union Frag { unsigned int u[4]; short8 v; };

__device__ inline unsigned short f32_to_bf16(float f) {
  unsigned int u = __float_as_uint(f);
  u += 0x7FFF + ((u >> 16) & 1);
  return (unsigned short)(u >> 16);
}

__device__ inline void async16(const unsigned short* g, unsigned short* l) {
  __builtin_amdgcn_global_load_lds(
      (const __attribute__((address_space(1))) unsigned int*)g,
      (__attribute__((address_space(3))) unsigned int*)l, 16, 0, 0);
}

// ---------------- prep: fp32 -> bf16 (+ w swizzle) ----------------
__global__ __launch_bounds__(256) void conv1d_prep(
    const float* __restrict__ x, const float* __restrict__ w,
    unsigned short* __restrict__ xb, unsigned short* __restrict__ wsw) {
  int bid = blockIdx.x;
  if (bid < N_BATCH * C_TOT) {              // x rows: fp32 -> bf16, pad to XROW
    const float* src = x + (size_t)bid * W_IN;
    unsigned short* dst = xb + (size_t)bid * XROW;
    for (int i = threadIdx.x; i < XROW / 4; i += 256) {
      int t = i * 4;
      ushort4 o;
      if (t < W_IN) {
        float4 v = *(const float4*)(src + t);
        o.x = f32_to_bf16(v.x); o.y = f32_to_bf16(v.y);
        o.z = f32_to_bf16(v.z); o.w = f32_to_bf16(v.w);
      } else {
        o.x = o.y = o.z = o.w = 0;
      }
      *(ushort4*)(dst + t) = o;
    }
  } else {                                   // w: [f][c][k] -> swizzled bf16
    int i4 = (bid - N_BATCH * C_TOT) * 256 + threadIdx.x;  // float4 index
    if (i4 < F_TOT * C_TOT * KW / 4) {
      int k4 = (i4 & 15) * 4;                // 0,4,...,60
      int c  = (i4 >> 4) & 63;
      int f  = i4 >> 10;
      float4 v = *(const float4*)&w[(size_t)i4 * 4];
      ushort4 o;
      o.x = f32_to_bf16(v.x); o.y = f32_to_bf16(v.y);
      o.z = f32_to_bf16(v.z); o.w = f32_to_bf16(v.w);
      int chunk = (k4 >> 3) ^ (f & 7);
      *(ushort4*)&wsw[((size_t)(c * F_TOT + f) * 8 + chunk) * 8 + (k4 & 7)] = o;
    }
  }
}

// ---------------- main GEMM ----------------
__global__ __launch_bounds__(256, 2) void conv1d_mfma(
    const unsigned short* __restrict__ xb, const unsigned short* __restrict__ wsw,
    const float* __restrict__ b, float* __restrict__ out) {
  __shared__ union SM {
    struct {
      unsigned short wls[2][CH * F_TOT * KW];  // 2 x 32 KB
      unsigned short xls[2][CH * 512];         // 2 x 2 KB
    } k;
    float tr[32 * TRS];                        // 33.3 KB transpose buffer
  } sm;

  const int tid  = threadIdx.x;
  const int lane = tid & 63;
  const int wv   = tid >> 6;     // 0..3
  const int q    = lane >> 4;    // 0..3
  const int col  = lane & 15;
  const int n    = blockIdx.y;
  const int t0   = blockIdx.x * T_BLK;
  const int fh2  = wv & 1;       // f half (64 f)
  const int th   = wv >> 1;      // t half (128 t)

  floatx4 acc[8][4];             // [ms][ft]
#pragma unroll
  for (int ms = 0; ms < 8; ++ms)
#pragma unroll
    for (int ft = 0; ft < 4; ++ft) acc[ms][ft] = (floatx4)0.0f;

  const unsigned short* xrow0 = xb + (size_t)(n * C_TOT) * XROW + t0;
#define STAGE(cg, p)                                                            \
  {                                                                             \
    const unsigned short* wbase = wsw + (size_t)(cg) * (CH * F_TOT * KW);       \
    _Pragma("unroll")                                                           \
    for (int s = 0; s < 8; ++s) {                                               \
      int off = (wv * 8 + s) * 512;                                             \
      async16(wbase + off + lane * 8, &sm.k.wls[p][off]);                       \
    }                                                                           \
    if (wv < CH)                                                                \
      async16(xrow0 + (size_t)((cg) * CH + wv) * XROW + lane * 8,               \
              &sm.k.xls[p][wv * 512]);                                          \
  }

  STAGE(0, 0)
  __syncthreads();

  for (int cg = 0; cg < C_TOT / CH; ++cg) {
    const int p = cg & 1;
    if (cg < C_TOT / CH - 1) STAGE(cg + 1, p ^ 1)

#pragma unroll
    for (int chl = 0; chl < CH; ++chl) {
      const unsigned short* xpb = &sm.k.xls[p][chl * 512];
      const unsigned short* wpb = &sm.k.wls[p][chl * F_TOT * KW];
#pragma unroll
      for (int h = 0; h < 2; ++h) {
        // A window: 16 shorts at byte offset 16*col + 256*th + 64*h + 16*q
        const int ab = 16 * col + 256 * th + 64 * h + 16 * q;
        const uint4 d0 = *(const uint4*)((const char*)xpb + ab);
        const uint4 d1 = *(const uint4*)((const char*)xpb + ab + 16);
        const unsigned int D[8] = {d0.x, d0.y, d0.z, d0.w, d1.x, d1.y, d1.z, d1.w};
        Frag A[8];
#pragma unroll
        for (int s = 0; s < 4; ++s)
#pragma unroll
          for (int i = 0; i < 4; ++i) {
            A[2 * s].u[i]     = D[s + i];                                // even ms: alias
            A[2 * s + 1].u[i] = (D[s + i] >> 16) | (D[s + i + 1] << 16); // odd ms: funnel
          }
        const int bs = ((h * 4 + q) ^ (col & 7)) * 8;  // swizzled k-chunk (shorts)
#pragma unroll
        for (int ft = 0; ft < 4; ++ft) {
          const short8 bf =
              *(const short8*)&wpb[(fh2 * 64 + ft * 16 + col) * KW + bs];
#pragma unroll
          for (int ms = 0; ms < 8; ++ms)
            acc[ms][ft] =
                __builtin_amdgcn_mfma_f32_16x16x32_bf16(A[ms].v, bf, acc[ms][ft], 0, 0, 0);
        }
      }
    }
    __syncthreads();
  }

  // ---- epilogue: LDS transpose to [f][t], then coalesced float4 stores ----
  // value acc[ms][ft][r]: t_loc = 32q + 8r + ms + 128*th, f = 64*fh2 + 16*ft + col
  const int fs_w  = fh2 * 16 + col;     // f-slot for writes
  const int fs_r  = tid >> 3;           // f-slot for reads (0..31)
  const int seg   = tid & 7;
  const int f_r   = (fs_r >> 4) * 64 + (fs_r & 15);
  const size_t ob = ((size_t)n * F_TOT) * OUT_W;

#pragma unroll 1
  for (int j = 0; j < 4; ++j) {         // round j handles ft == j
    // write phase: 8 x ds_write_b128 per lane
#pragma unroll
    for (int r = 0; r < 4; ++r)
#pragma unroll
      for (int g = 0; g < 2; ++g) {
        float4 vv;
        vv.x = acc[g * 4 + 0][j][r];
        vv.y = acc[g * 4 + 1][j][r];
        vv.z = acc[g * 4 + 2][j][r];
        vv.w = acc[g * 4 + 3][j][r];
        int tl = 32 * q + 8 * r + 4 * g + 128 * th;
        *(float4*)&sm.tr[fs_w * TRS + tl] = vv;
      }
    __syncthreads();
    // read + store phase: 8 x (ds_read_b128 + global_store_dwordx4) per thread
    const int f = f_r + 16 * j;
    const float bias = b[f];
    const size_t obf = ob + (size_t)f * OUT_W;
#pragma unroll
    for (int j2 = 0; j2 < 8; ++j2) {
      int tl = seg * 4 + 32 * j2;
      float4 vv = *(const float4*)&sm.tr[fs_r * TRS + tl];
      vv.x += bias; vv.y += bias; vv.z += bias; vv.w += bias;
      int t = t0 + tl;
      if (t + 3 < OUT_W) {
        *(float4*)&out[obf + t] = vv;
      } else {
        float e[4] = {vv.x, vv.y, vv.z, vv.w};
#pragma unroll
        for (int u = 0; u < 4; ++u)
          if (t + u < OUT_W) out[obf + t + u] = e[u];
      }
    }
    __syncthreads();
  }
}

extern "C" void kernel_launch(void* const* d_in, const int* in_sizes, int n_in,
                              void* d_out, int out_size, void* d_ws, size_t ws_size,
                              hipStream_t stream) {
  const float* x = (const float*)d_in[0];
  const float* w = (const float*)d_in[1];
  const float* b = (const float*)d_in[2];
  float* out = (float*)d_out;

  unsigned short* wsw = (unsigned short*)d_ws;                      // 1 MB
  unsigned short* xb  = (unsigned short*)((char*)d_ws + (1 << 20)); // 17.8 MB

  conv1d_prep<<<N_BATCH * C_TOT + 512, 256, 0, stream>>>(x, w, xb, wsw);

  dim3 grid((OUT_W + T_BLK - 1) / T_BLK, N_BATCH);  // 16 x 32 = 512 blocks
  conv1d_mfma<<<grid, 256, 0, stream>>>(xb, wsw, b, out);
}

// Round 5
// 192.152 us; speedup vs baseline: 2.2167x; 2.2167x over previous
//
#include <hip/hip_runtime.h>

// Conv1d as implicit GEMM on MFMA bf16 — R5.
// out[n,f,t] = sum_{c,k} x[n,c,t+k] * w[f,c,k] + b[f]
// N=32, C=64, W=4096, F=128, WW=64, out_W=4033. Output fp32.
//
// R5 vs R4:
//  * Epilogue fully unrolled (compile-time acc indices). R4's runtime-j
//    indexing demoted acc[] to scratch -> 2.28 GB spill traffic. THE fix.
//  * x staged inline (fp32 load -> cvt -> ds_write, split around compute);
//    prep kernel now converts/swizzles only w (4 MB).

#define C_TOT   64
#define F_TOT   128
#define KW      64
#define OUT_W   4033
#define W_IN    4096
#define N_BATCH 32
#define T_BLK   256
#define CH      2             // channels per pipeline stage
#define XWIN    320           // shorts needed per channel window (256 + 64)
#define XSTR    384           // xls channel stride (shorts)
#define TRS     260           // transpose LDS row stride (dwords)

typedef __attribute__((ext_vector_type(8))) short  short8;
typedef __attribute__((ext_vector_type(4))) float  floatx4;

union Frag { unsigned int u[4]; short8 v; };

__device__ inline unsigned short f32_to_bf16(float f) {
  unsigned int u = __float_as_uint(f);
  u += 0x7FFF + ((u >> 16) & 1);
  return (unsigned short)(u >> 16);
}

__device__ inline void async16(const unsigned short* g, unsigned short* l) {
  __builtin_amdgcn_global_load_lds(
      (const __attribute__((address_space(1))) unsigned int*)g,
      (__attribute__((address_space(3))) unsigned int*)l, 16, 0, 0);
}

// ---------------- prep: w fp32 -> bf16 swizzled [c][f][(k>>3)^(f&7)][k&7] ----
__global__ __launch_bounds__(256) void conv1d_prep(
    const float* __restrict__ w, unsigned short* __restrict__ wsw) {
  int i4 = blockIdx.x * 256 + threadIdx.x;   // float4 index into w
  if (i4 < F_TOT * C_TOT * KW / 4) {
    int k4 = (i4 & 15) * 4;
    int c  = (i4 >> 4) & 63;
    int f  = i4 >> 10;
    float4 v = *(const float4*)&w[(size_t)i4 * 4];
    ushort4 o;
    o.x = f32_to_bf16(v.x); o.y = f32_to_bf16(v.y);
    o.z = f32_to_bf16(v.z); o.w = f32_to_bf16(v.w);
    int chunk = (k4 >> 3) ^ (f & 7);
    *(ushort4*)&wsw[((size_t)(c * F_TOT + f) * 8 + chunk) * 8 + (k4 & 7)] = o;
  }
}

// ---------------- main GEMM ----------------
__global__ __launch_bounds__(256, 2) void conv1d_mfma(
    const float* __restrict__ x, const unsigned short* __restrict__ wsw,
    const float* __restrict__ b, float* __restrict__ out) {
  __shared__ union SM {
    struct {
      unsigned short wls[2][CH * F_TOT * KW];  // 2 x 32 KB
      unsigned short xls[2][CH * XSTR];        // 2 x 1.5 KB
    } k;
    float tr[32 * TRS];                        // 33.3 KB transpose buffer
  } sm;

  const int tid  = threadIdx.x;
  const int lane = tid & 63;
  const int wv   = tid >> 6;     // 0..3
  const int q    = lane >> 4;    // 0..3
  const int col  = lane & 15;
  const int n    = blockIdx.y;
  const int t0   = blockIdx.x * T_BLK;
  const int fh2  = wv & 1;       // f half (64 f)
  const int th   = wv >> 1;      // t half (128 t)

  // x staging role: 160 threads, one float4 each (2 ch x 80 float4)
  const int xc = tid / 80;              // channel-within-group
  const int xi = (tid - xc * 80) * 4;   // short offset 0..316
  const float* xrowb = x + (size_t)n * C_TOT * W_IN;

  floatx4 acc[8][4];             // [ms][ft]
#pragma unroll
  for (int ms = 0; ms < 8; ++ms)
#pragma unroll
    for (int ft = 0; ft < 4; ++ft) acc[ms][ft] = (floatx4)0.0f;

#define LOAD_X(cgx, vv)                                                         \
  {                                                                             \
    const float* src = xrowb + (size_t)((cgx) * CH + xc) * W_IN;                \
    int gt = t0 + xi;                                                           \
    if (gt + 3 < W_IN) vv = *(const float4*)(src + gt);                         \
    else {                                                                      \
      if (gt < W_IN)     vv.x = src[gt];                                        \
      if (gt + 1 < W_IN) vv.y = src[gt + 1];                                    \
      if (gt + 2 < W_IN) vv.z = src[gt + 2];                                    \
    }                                                                           \
  }

#define WRITE_X(p, vv)                                                          \
  {                                                                             \
    ushort4 o;                                                                  \
    o.x = f32_to_bf16(vv.x); o.y = f32_to_bf16(vv.y);                           \
    o.z = f32_to_bf16(vv.z); o.w = f32_to_bf16(vv.w);                           \
    *(ushort4*)&sm.k.xls[p][xc * XSTR + xi] = o;                                \
  }

#define STAGE_W(cg, p)                                                          \
  {                                                                             \
    const unsigned short* wbase = wsw + (size_t)(cg) * (CH * F_TOT * KW);       \
    _Pragma("unroll")                                                           \
    for (int s = 0; s < 8; ++s) {                                               \
      int off = (wv * 8 + s) * 512;                                             \
      async16(wbase + off + lane * 8, &sm.k.wls[p][off]);                       \
    }                                                                           \
  }

  // prologue: stage cg=0 into buffer 0
  if (tid < 160) {
    float4 xv = {0.f, 0.f, 0.f, 0.f};
    LOAD_X(0, xv)
    WRITE_X(0, xv)
  }
  STAGE_W(0, 0)
  __syncthreads();

  for (int cg = 0; cg < C_TOT / CH; ++cg) {
    const int p = cg & 1;
    const bool pre = (cg < C_TOT / CH - 1);
    float4 xv = {0.f, 0.f, 0.f, 0.f};
    if (pre && tid < 160) LOAD_X(cg + 1, xv)   // issue loads; land during compute
    if (pre) STAGE_W(cg + 1, p ^ 1)

#pragma unroll
    for (int chl = 0; chl < CH; ++chl) {
      const unsigned short* xpb = &sm.k.xls[p][chl * XSTR];
      const unsigned short* wpb = &sm.k.wls[p][chl * F_TOT * KW];
#pragma unroll
      for (int h = 0; h < 2; ++h) {
        // A window: 16 shorts at byte offset 16*col + 256*th + 64*h + 16*q
        const int ab = 16 * col + 256 * th + 64 * h + 16 * q;
        const uint4 d0 = *(const uint4*)((const char*)xpb + ab);
        const uint4 d1 = *(const uint4*)((const char*)xpb + ab + 16);
        const unsigned int D[8] = {d0.x, d0.y, d0.z, d0.w, d1.x, d1.y, d1.z, d1.w};
        Frag A[8];
#pragma unroll
        for (int s = 0; s < 4; ++s)
#pragma unroll
          for (int i = 0; i < 4; ++i) {
            A[2 * s].u[i]     = D[s + i];                                // even ms
            A[2 * s + 1].u[i] = (D[s + i] >> 16) | (D[s + i + 1] << 16); // odd ms
          }
        const int bs = ((h * 4 + q) ^ (col & 7)) * 8;  // swizzled k-chunk (shorts)
#pragma unroll
        for (int ft = 0; ft < 4; ++ft) {
          const short8 bf =
              *(const short8*)&wpb[(fh2 * 64 + ft * 16 + col) * KW + bs];
#pragma unroll
          for (int ms = 0; ms < 8; ++ms)
            acc[ms][ft] =
                __builtin_amdgcn_mfma_f32_16x16x32_bf16(A[ms].v, bf, acc[ms][ft], 0, 0, 0);
        }
      }
    }
    if (pre && tid < 160) WRITE_X(p ^ 1, xv)
    __syncthreads();
  }

  // ---- epilogue: LDS transpose to [f][t], coalesced float4 stores ----
  // acc[ms][ft][r]: t_loc = 32q + 8r + ms + 128*th, f = 64*fh2 + 16*ft + col
  const int fs_w  = fh2 * 16 + col;     // f-slot for writes (0..31)
  const int fs_r  = tid >> 3;           // f-slot for reads (0..31)
  const int seg   = tid & 7;
  const int f_r   = (fs_r >> 4) * 64 + (fs_r & 15);
  const size_t ob = ((size_t)n * F_TOT) * OUT_W;

#pragma unroll
  for (int j = 0; j < 4; ++j) {         // round j handles ft == j (COMPILE-TIME)
#pragma unroll
    for (int r = 0; r < 4; ++r)
#pragma unroll
      for (int g = 0; g < 2; ++g) {
        float4 vv;
        vv.x = acc[g * 4 + 0][j][r];
        vv.y = acc[g * 4 + 1][j][r];
        vv.z = acc[g * 4 + 2][j][r];
        vv.w = acc[g * 4 + 3][j][r];
        int tl = 32 * q + 8 * r + 4 * g + 128 * th;
        *(float4*)&sm.tr[fs_w * TRS + tl] = vv;
      }
    __syncthreads();
    const int f = f_r + 16 * j;
    const float bias = b[f];
    const size_t obf = ob + (size_t)f * OUT_W;
#pragma unroll
    for (int j2 = 0; j2 < 8; ++j2) {
      int tl = seg * 4 + 32 * j2;
      float4 vv = *(const float4*)&sm.tr[fs_r * TRS + tl];
      vv.x += bias; vv.y += bias; vv.z += bias; vv.w += bias;
      int t = t0 + tl;
      if (t + 3 < OUT_W) {
        *(float4*)&out[obf + t] = vv;
      } else {
        float e[4] = {vv.x, vv.y, vv.z, vv.w};
#pragma unroll
        for (int u = 0; u < 4; ++u)
          if (t + u < OUT_W) out[obf + t + u] = e[u];
      }
    }
    __syncthreads();
  }
}

extern "C" void kernel_launch(void* const* d_in, const int* in_sizes, int n_in,
                              void* d_out, int out_size, void* d_ws, size_t ws_size,
                              hipStream_t stream) {
  const float* x = (const float*)d_in[0];
  const float* w = (const float*)d_in[1];
  const float* b = (const float*)d_in[2];
  float* out = (float*)d_out;

  unsigned short* wsw = (unsigned short*)d_ws;   // 1 MB bf16 swizzled w

  conv1d_prep<<<(F_TOT * C_TOT * KW / 4 + 255) / 256, 256, 0, stream>>>(w, wsw);

  dim3 grid((OUT_W + T_BLK - 1) / T_BLK, N_BATCH);  // 16 x 32 = 512 blocks
  conv1d_mfma<<<grid, 256, 0, stream>>>(x, wsw, b, out);
}